// Round 20
// baseline (119.755 us; speedup 1.0000x reference)
//
#include <hip/hip_runtime.h>
#include <hip/hip_bf16.h>

#define HEADS  16
#define DIMH   64
#define NBATCH 2
#define SEQ    2048
#define DMODEL 1024
#define MROWS  (NBATCH * SEQ)   // 4096

typedef __attribute__((ext_vector_type(8)))  short bf16x8;
typedef __attribute__((ext_vector_type(4)))  float f32x4;
typedef __attribute__((ext_vector_type(16))) float f32x16;
typedef __attribute__((ext_vector_type(4)))  float float4v;
typedef __attribute__((ext_vector_type(4)))  short short4v;
typedef __attribute__((ext_vector_type(8)))  short short8v;

__device__ inline void glds16(const void* g, void* l) {
    __builtin_amdgcn_global_load_lds(
        (const __attribute__((address_space(1))) unsigned int*)g,
        (__attribute__((address_space(3))) unsigned int*)l, 16, 0, 0);
}

#define WAIT_VMCNT(N) asm volatile("s_waitcnt vmcnt(" #N ")" ::: "memory")
#define BARRIER() do { __builtin_amdgcn_s_barrier(); asm volatile("" ::: "memory"); } while (0)

// ------ prep: hs f32->bf16 cast + 3 weight transposes, ONE launch ---------
__global__ void prep_kernel(const float* __restrict__ hs,
                            const float* __restrict__ Wq,
                            const float* __restrict__ Wkv,
                            const float* __restrict__ Wout,
                            __hip_bfloat16* __restrict__ hsb,
                            __hip_bfloat16* __restrict__ WqT,
                            __hip_bfloat16* __restrict__ WkvT,
                            __hip_bfloat16* __restrict__ WoT) {
    __shared__ float tile[64][65];
    const int tid = threadIdx.x;
    const int bid = blockIdx.x;
    if (bid < 768) {
        const int w = bid >> 8;            // 0..2
        const int tnum = bid & 255;        // 0..255
        const int bx = tnum & 15;          // o-tile
        const int by = tnum >> 4;          // i-tile
        const float* __restrict__ W = (w == 0) ? Wq : (w == 1) ? Wkv : Wout;
        __hip_bfloat16* __restrict__ WT = (w == 0) ? WqT : (w == 1) ? WkvT : WoT;
        const int ty = tid >> 6, tx = tid & 63;
#pragma unroll
        for (int r = 0; r < 16; ++r)
            tile[ty * 16 + r][tx] = W[(size_t)(by * 64 + ty * 16 + r) * DMODEL + bx * 64 + tx];
        __syncthreads();
#pragma unroll
        for (int r = 0; r < 16; ++r)
            WT[(size_t)(bx * 64 + ty * 16 + r) * DMODEL + by * 64 + tx] =
                __float2bfloat16(tile[tx][ty * 16 + r]);
    } else {
        const int cb = bid - 768;          // 0..1023
#pragma unroll
        for (int jj = 0; jj < 4; ++jj) {
            int i = cb * 1024 + jj * 256 + tid;   // float4-group index
            float4v v = reinterpret_cast<const float4v*>(hs)[i];
            union { short4v s; __hip_bfloat16 h[4]; } u;
#pragma unroll
            for (int j = 0; j < 4; ++j) u.h[j] = __float2bfloat16(v[j]);
            reinterpret_cast<short4v*>(hsb)[i] = u.s;
        }
    }
}

// -------- fused Q/KV projection GEMM (BM=128, BN=128, grid 512) ------------
// 2 blocks/CU. vtb stored with s-index bits 2&3 swapped within each 16-block
// so the attention kernel's PV fragment chunks are contiguous global bytes.
__launch_bounds__(512, 4)
__global__ void proj_kernel(const __hip_bfloat16* __restrict__ hsb,
                            const __hip_bfloat16* __restrict__ WqT,
                            const __hip_bfloat16* __restrict__ WkvT,
                            __hip_bfloat16* __restrict__ qb,
                            __hip_bfloat16* __restrict__ kb,
                            __hip_bfloat16* __restrict__ vtb) {
    __shared__ __align__(16) char SLDS[49152];
    char (*Alds)[8192] = (char (*)[8192])SLDS;               // 3 x 8KB
    char (*Blds)[8192] = (char (*)[8192])(SLDS + 24576);     // 3 x 8KB
    char* CT = SLDS;                                         // 32KB reuse

    const int tid  = threadIdx.x;         // 0..511
    const int wave = tid >> 6;            // 0..7
    const int lane = tid & 63;
    const int lr = lane & 15;
    const int lk = lane >> 4;
    const int wm = wave >> 1, wn = wave & 1;   // 4M x 2N, wave tile 32x64

    // bijective XCD swizzle: 512 blocks, 64 contiguous ids per XCD
    int bid = blockIdx.x;
    bid = (bid & 7) * 64 + (bid >> 3);
    const int xt = bid & 15;              // q: 0..7, kv: 8..15
    const int mt = bid >> 4;              // 0..31
    const bool is_q = xt < 8;
    const int mbase = mt * 128;
    const int nbase = (xt & 7) * 128;
    const __hip_bfloat16* __restrict__ WT = is_q ? WqT : WkvT;

    const char* __restrict__ Ab = (const char*)(hsb + (size_t)mbase * DMODEL);
    const char* __restrict__ Bb = (const char*)(WT + (size_t)nbase * DMODEL);

    auto stage = [&](int buf, int k0) {
        const size_t colb = (size_t)k0 * 2 + lk * 16;
        const size_t rowoff = (size_t)(wave * 16 + lr) * (DMODEL * 2);
        glds16(Ab + rowoff + colb, &Alds[buf][wave * 1024]);
        glds16(Bb + rowoff + colb, &Blds[buf][wave * 1024]);
    };

    stage(0, 0);
    stage(1, 32);

    f32x4 acc[2][4] = {};
    int c0 = 0;
    for (int t = 0; t < DMODEL / 32; ++t) {
        if (t < DMODEL / 32 - 1) WAIT_VMCNT(2); else WAIT_VMCNT(0);
        BARRIER();
        if (t + 2 < DMODEL / 32) {
            int sb = c0 + 2; if (sb >= 3) sb -= 3;
            stage(sb, (t + 2) * 32);
        }
        bf16x8 af[2], bfr[4];
#pragma unroll
        for (int i = 0; i < 2; ++i)
            af[i] = *reinterpret_cast<const bf16x8*>(&Alds[c0][(wm * 2 + i) * 1024 + lane * 16]);
#pragma unroll
        for (int j = 0; j < 4; ++j)
            bfr[j] = *reinterpret_cast<const bf16x8*>(&Blds[c0][(wn * 4 + j) * 1024 + lane * 16]);
#pragma unroll
        for (int i = 0; i < 2; ++i)
#pragma unroll
            for (int j = 0; j < 4; ++j)
                acc[i][j] = __builtin_amdgcn_mfma_f32_16x16x32_bf16(af[i], bfr[j], acc[i][j], 0, 0, 0);
        c0 = (c0 + 1 == 3) ? 0 : c0 + 1;
    }

    // ================= epilogue via LDS (coalesced stores) =================
    const float qscale = is_q ? 0.125f : 1.0f;   // fold attention scale into Q
    const int b_ = mbase >> 11;
    const int s0 = mbase & (SEQ - 1);
    const int h0 = nbase >> 6;
    BARRIER();   // staging LDS dead

    // 1) acc -> CT [128m][128n] bf16, key = ((m>>2)&7)<<4
#pragma unroll
    for (int i = 0; i < 2; ++i)
#pragma unroll
        for (int j = 0; j < 4; ++j)
#pragma unroll
            for (int r = 0; r < 4; ++r) {
                int m = wm * 32 + i * 16 + lk * 4 + r;
                int n = wn * 64 + j * 16 + lr;
                *reinterpret_cast<__hip_bfloat16*>(
                    &CT[m * 256 + ((n * 2) ^ (((m >> 2) & 7) << 4))]) =
                    __float2bfloat16(acc[i][j][r] * qscale);
            }
    BARRIER();

    // 2) coalesced q/k stores: 8-lane groups write 128B head-segment runs
    __hip_bfloat16* __restrict__ dst0 = is_q ? qb : kb;
#pragma unroll
    for (int p = 0; p < 4; ++p) {
        int g = p * 64 + (tid >> 3);      // 0..255
        int m = g >> 1, hseg = g & 1, o = tid & 7;
        int key = ((m >> 2) & 7) << 4;
        bf16x8 val = *reinterpret_cast<const bf16x8*>(
            &CT[m * 256 + ((hseg * 128 + o * 16) ^ key)]);
        *reinterpret_cast<bf16x8*>(
            &dst0[(((size_t)b_ * HEADS + h0 + hseg) * SEQ + s0 + m) * DIMH + o * 8]) = val;
    }

    if (!is_q) {
        BARRIER();
        // 3) acc -> CT2 [128n][128m] bf16, key2 = ((n&7)<<4)
#pragma unroll
        for (int i = 0; i < 2; ++i)
#pragma unroll
            for (int j = 0; j < 4; ++j)
#pragma unroll
                for (int r = 0; r < 4; ++r) {
                    int m = wm * 32 + i * 16 + lk * 4 + r;
                    int n = wn * 64 + j * 16 + lr;
                    *reinterpret_cast<__hip_bfloat16*>(
                        &CT[n * 256 + ((m * 2) ^ ((n & 7) << 4))]) =
                        __float2bfloat16(acc[i][j][r]);
                }
        BARRIER();
        // 4) coalesced vtb stores, s bits2&3 swapped: dest run t'=16m'+8H+j
#pragma unroll
        for (int p = 0; p < 4; ++p) {
            int g = p * 64 + (tid >> 3);      // 0..255
            int n = g >> 1, half = g & 1, o = tid & 7;
            int key2 = (n & 7) << 4;
            int D = half * 64 + o * 8;
            int mm = D >> 4, H = o & 1;
            union { unsigned long long d[2]; bf16x8 v; } val;
            val.d[0] = *reinterpret_cast<const unsigned long long*>(
                &CT[n * 256 + ((mm * 32 + H * 8) ^ key2)]);
            val.d[1] = *reinterpret_cast<const unsigned long long*>(
                &CT[n * 256 + ((mm * 32 + 16 + H * 8) ^ key2)]);
            int h = h0 + (n >> 6);
            int dh = n & 63;
            *reinterpret_cast<bf16x8*>(
                &vtb[(((size_t)b_ * HEADS + h) * DIMH + dh) * SEQ + s0 + D]) = val.v;
        }
    }
}

// ---- output projection + FUSED COMBINE: A = bf16(po0+po1) via dual glds ---
// BM=128, BN=128, 8 waves, 3 buffers, 72KB LDS. Both bf16 partial panels
// staged by global_load_lds (allocator-proof); add+pack in VALU at fragment
// read (overlaps MFMA pipe). 3 glds/wave/stage -> steady vmcnt(3).
__launch_bounds__(512, 2)
__global__ void outproj_kernel(const __hip_bfloat16* __restrict__ po,
                               const __hip_bfloat16* __restrict__ WoT,
                               const float* __restrict__ bout,
                               float* __restrict__ out) {
    __shared__ __align__(16) char A0lds[3][8192];
    __shared__ __align__(16) char A1lds[3][8192];
    __shared__ __align__(16) char Blds[3][8192];
    const int tid  = threadIdx.x;
    const int wave = tid >> 6;
    const int lane = tid & 63;
    const int lr = lane & 15;
    const int lk = lane >> 4;
    const int wm = wave >> 1, wn = wave & 1;   // 4M x 2N, wave tile 32x64

    // bijective XCD swizzle: 256 blocks, 32 contiguous ids per XCD
    int bid = blockIdx.x;
    bid = (bid & 7) * 32 + (bid >> 3);
    const int xt = bid & 7;
    const int mt = bid >> 3;
    const int mbase = mt * 128;
    const int nbase = xt * 128;

    const char* __restrict__ A0b = (const char*)(po + (size_t)mbase * DMODEL);
    const char* __restrict__ A1b = (const char*)(po + (size_t)(MROWS + mbase) * DMODEL);
    const char* __restrict__ Bb  = (const char*)(WoT + (size_t)nbase * DMODEL);

    auto stage = [&](int buf, int k0) {
        const size_t colb = (size_t)k0 * 2 + lk * 16;
        const size_t rowoff = (size_t)(wave * 16 + lr) * (DMODEL * 2);
        glds16(A0b + rowoff + colb, &A0lds[buf][wave * 1024]);
        glds16(A1b + rowoff + colb, &A1lds[buf][wave * 1024]);
        glds16(Bb + rowoff + colb, &Blds[buf][wave * 1024]);
    };

    stage(0, 0);
    stage(1, 32);

    // bf16(a+b) elementwise, f32 accumulate (same rounding as old combine)
    auto addpack = [](bf16x8 x, bf16x8 y) -> bf16x8 {
        union { bf16x8 v; __hip_bfloat16 h[8]; } ux, uy, uo;
        ux.v = x; uy.v = y;
#pragma unroll
        for (int e = 0; e < 8; ++e)
            uo.h[e] = __float2bfloat16(__bfloat162float(ux.h[e]) +
                                       __bfloat162float(uy.h[e]));
        return uo.v;
    };

    f32x4 acc[2][4] = {};
    int c0 = 0;
    for (int t = 0; t < DMODEL / 32; ++t) {
        if (t < DMODEL / 32 - 1) WAIT_VMCNT(3); else WAIT_VMCNT(0);
        BARRIER();
        if (t + 2 < DMODEL / 32) {
            int sb = c0 + 2; if (sb >= 3) sb -= 3;
            stage(sb, (t + 2) * 32);
        }
        bf16x8 af[2], bfr[4];
#pragma unroll
        for (int i = 0; i < 2; ++i) {
            bf16x8 a0 = *reinterpret_cast<const bf16x8*>(&A0lds[c0][(wm * 2 + i) * 1024 + lane * 16]);
            bf16x8 a1 = *reinterpret_cast<const bf16x8*>(&A1lds[c0][(wm * 2 + i) * 1024 + lane * 16]);
            af[i] = addpack(a0, a1);
        }
#pragma unroll
        for (int j = 0; j < 4; ++j)
            bfr[j] = *reinterpret_cast<const bf16x8*>(&Blds[c0][(wn * 4 + j) * 1024 + lane * 16]);
#pragma unroll
        for (int i = 0; i < 2; ++i)
#pragma unroll
            for (int j = 0; j < 4; ++j)
                acc[i][j] = __builtin_amdgcn_mfma_f32_16x16x32_bf16(af[i], bfr[j], acc[i][j], 0, 0, 0);
        c0 = (c0 + 1 == 3) ? 0 : c0 + 1;
    }

#pragma unroll
    for (int j = 0; j < 4; ++j) {
        const int n = nbase + wn * 64 + j * 16 + lr;
        const float bias = bout[n];
#pragma unroll
        for (int i = 0; i < 2; ++i) {
#pragma unroll
            for (int r = 0; r < 4; ++r) {
                int m = mbase + wm * 32 + i * 16 + lk * 4 + r;
                out[(size_t)m * DMODEL + n] = acc[i][j][r] + bias;
            }
        }
    }
}

// ------- fused ReLU attention: KVBLK=128 (1 barrier per 128 t) -------------
// grid 256 = 32 bh x 4 qblk x 2 ts; 512 thr; wave owns 64 q x 1024 t.
// 128-t K/V tiles in 16 fragment-order runs each (32KB/buf), 3 buffers (96KB);
// two 64-t compute sub-steps per barrier; counted vmcnt(4).
__launch_bounds__(512, 2)
__global__ void attn_kernel(const __hip_bfloat16* __restrict__ qb,
                            const __hip_bfloat16* __restrict__ kb,
                            const __hip_bfloat16* __restrict__ vtb,
                            __hip_bfloat16* __restrict__ po) {
    __shared__ __align__(16) char Klds[3][16384];
    __shared__ __align__(16) char Vlds[3][16384];
    const int lane = threadIdx.x & 63;
    const int wave = threadIdx.x >> 6;    // 0..7
    const int l32  = lane & 31;
    const int hi   = lane >> 5;

    int bid = blockIdx.x;
    bid = (bid & 7) * 32 + (bid >> 3);    // bijective XCD swizzle (256%8==0)
    const int ts   = bid & 1;             // t-split half
    const int qblk = (bid >> 1) & 3;      // 0..3
    const int bh   = bid >> 3;            // 0..31
    const int b_ = bh >> 4, h = bh & 15;
    const int qbase = qblk * 512 + wave * 64;
    const int tbeg = ts * (SEQ / 2);

    const __hip_bfloat16* __restrict__ Q = qb + (size_t)bh * SEQ * DIMH;
    const char* __restrict__ Kg = (const char*)(kb  + (size_t)bh * SEQ * DIMH);
    const char* __restrict__ Vg = (const char*)(vtb + (size_t)bh * DIMH * SEQ);

    // two q-groups of 32 rows each
    bf16x8 qf[2][4];
#pragma unroll
    for (int g = 0; g < 2; ++g)
#pragma unroll
        for (int ks = 0; ks < 4; ++ks)
            qf[g][ks] = *reinterpret_cast<const bf16x8*>(
                &Q[(size_t)(qbase + g * 32 + l32) * DIMH + ks * 16 + hi * 8]);

    // 128-t tile: 16 K runs + 16 V runs; wave stages K {wave, 8+wave},
    // V {wave, 8+wave} (4 glds).
    auto stage = [&](int buf, int t0) {
        const int krow = (wave >> 2) * 32 + l32;
        const int kcol = (wave & 3) * 32 + hi * 16;
        glds16(Kg + (size_t)(t0 + krow) * 128 + kcol,       &Klds[buf][wave * 1024]);
        glds16(Kg + (size_t)(t0 + 64 + krow) * 128 + kcol,  &Klds[buf][(8 + wave) * 1024]);
        const size_t vrow = (size_t)((wave & 1) * 32 + l32) * (SEQ * 2);
        const int vcol = (wave >> 1) * 32 + hi * 16;
        glds16(Vg + vrow + (size_t)t0 * 2 + vcol,           &Vlds[buf][wave * 1024]);
        glds16(Vg + vrow + (size_t)(t0 + 64) * 2 + vcol,    &Vlds[buf][(8 + wave) * 1024]);
    };

    f32x16 acco[2][2] = {};   // [qgroup][nt]

    // one 64-t sub-step: u=0 -> runs 0..7, u=1 -> runs 8..15
    auto compute = [&](const char* Kc, const char* Vc, int u) {
        const int ro = u * 8192;
        f32x16 sp[2][2] = {};  // [qgroup][t-32-half]
        __builtin_amdgcn_s_setprio(1);
#pragma unroll
        for (int ks = 0; ks < 4; ++ks) {
            bf16x8 k0f = *reinterpret_cast<const bf16x8*>(Kc + ro + ks * 1024 + lane * 16);
            bf16x8 k1f = *reinterpret_cast<const bf16x8*>(Kc + ro + (4 + ks) * 1024 + lane * 16);
            sp[0][0] = __builtin_amdgcn_mfma_f32_32x32x16_bf16(k0f, qf[0][ks], sp[0][0], 0, 0, 0);
            sp[0][1] = __builtin_amdgcn_mfma_f32_32x32x16_bf16(k1f, qf[0][ks], sp[0][1], 0, 0, 0);
            sp[1][0] = __builtin_amdgcn_mfma_f32_32x32x16_bf16(k0f, qf[1][ks], sp[1][0], 0, 0, 0);
            sp[1][1] = __builtin_amdgcn_mfma_f32_32x32x16_bf16(k1f, qf[1][ks], sp[1][1], 0, 0, 0);
        }
#pragma unroll
        for (int kt = 0; kt < 4; ++kt) {
            bf16x8 v0 = *reinterpret_cast<const bf16x8*>(Vc + ro + (kt * 2 + 0) * 1024 + lane * 16);
            bf16x8 v1 = *reinterpret_cast<const bf16x8*>(Vc + ro + (kt * 2 + 1) * 1024 + lane * 16);
            const int rb = (kt & 1) * 8;
#pragma unroll
            for (int g = 0; g < 2; ++g) {
                union { __hip_bfloat16 hh[8]; bf16x8 v; } pa;
#pragma unroll
                for (int j = 0; j < 8; ++j) {
                    float x = (kt < 2) ? sp[g][0][rb + j] : sp[g][1][rb + j];
                    pa.hh[j] = __float2bfloat16(fmaxf(x, 0.f));
                }
                acco[g][0] = __builtin_amdgcn_mfma_f32_32x32x16_bf16(pa.v, v0, acco[g][0], 0, 0, 0);
                acco[g][1] = __builtin_amdgcn_mfma_f32_32x32x16_bf16(pa.v, v1, acco[g][1], 0, 0, 0);
            }
        }
        __builtin_amdgcn_s_setprio(0);
    };

    const int NT = SEQ / 2 / 128;   // 8 tiles per t-half
    stage(0, tbeg);
    stage(1, tbeg + 128);

    for (int t = 0; t < NT; ++t) {
        if (t < NT - 1) WAIT_VMCNT(4); else WAIT_VMCNT(0);
        BARRIER();
        if (t + 2 < NT) {
            int sb = t + 2; sb -= (sb / 3) * 3;   // (t+2)%3
            stage(sb, tbeg + (t + 2) * 128);
        }
        const int c0 = t % 3;
        compute(Klds[c0], Vlds[c0], 0);
        compute(Klds[c0], Vlds[c0], 1);
    }

    // ---- epilogue: bf16 partial, row q = qbase + g*32 + (r&3)+8*(r>>2)+4*hi ----
    __hip_bfloat16* __restrict__ PO = po + (size_t)ts * MROWS * DMODEL;
#pragma unroll
    for (int g = 0; g < 2; ++g)
#pragma unroll
        for (int nt = 0; nt < 2; ++nt)
#pragma unroll
            for (int r = 0; r < 16; ++r) {
                int q = qbase + g * 32 + (r & 3) + 8 * (r >> 2) + 4 * hi;
                PO[(size_t)(b_ * SEQ + q) * DMODEL + h * 64 + nt * 32 + l32] =
                    __float2bfloat16(acco[g][nt][r]);
            }
}

extern "C" void kernel_launch(void* const* d_in, const int* in_sizes, int n_in,
                              void* d_out, int out_size, void* d_ws, size_t ws_size,
                              hipStream_t stream) {
    const float* hs   = (const float*)d_in[0];
    const float* Wq   = (const float*)d_in[1];
    const float* Wkv  = (const float*)d_in[2];
    const float* Wout = (const float*)d_in[3];
    const float* bout = (const float*)d_in[4];
    float* out = (float*)d_out;

    char* ws = (char*)d_ws;
    size_t off = 0;
    auto alloc = [&](size_t bytes) { char* p = ws + off; off += bytes; return p; };
    __hip_bfloat16* hsb  = (__hip_bfloat16*)alloc((size_t)MROWS * DMODEL * 2); // dead after proj
    __hip_bfloat16* WqT  = (__hip_bfloat16*)alloc((size_t)DMODEL * DMODEL * 2);
    __hip_bfloat16* WkvT = (__hip_bfloat16*)alloc((size_t)DMODEL * DMODEL * 2);
    __hip_bfloat16* WoT  = (__hip_bfloat16*)alloc((size_t)DMODEL * DMODEL * 2);
    __hip_bfloat16* qb   = (__hip_bfloat16*)alloc((size_t)MROWS * DMODEL * 2);
    __hip_bfloat16* kb   = (__hip_bfloat16*)alloc((size_t)MROWS * DMODEL * 2);
    __hip_bfloat16* vtb  = (__hip_bfloat16*)alloc((size_t)MROWS * DMODEL * 2);
    __hip_bfloat16* po   = (__hip_bfloat16*)alloc((size_t)2 * MROWS * DMODEL * 2); // 16MB bf16

    // 1. fused cast + transposes: ONE launch
    prep_kernel<<<1792, 256, 0, stream>>>(hs, Wq, Wkv, Wout, hsb, WqT, WkvT, WoT);

    // 2. fused Q/KV projection (Q pre-scaled by 1/8): 512 blocks x 512 thr
    proj_kernel<<<512, 512, 0, stream>>>(hsb, WqT, WkvT, qb, kb, vtb);

    // 3. fused relu attention: 256 blocks x 512 thr, KVBLK=128, t-split
    attn_kernel<<<256, 512, 0, stream>>>(qb, kb, vtb, po);

    // 4. output projection + fused combine: 256 blocks x 512 thr
    outproj_kernel<<<256, 512, 0, stream>>>(po, WoT, bout, out);
}

// Round 21
// 112.443 us; speedup vs baseline: 1.0650x; 1.0650x over previous
//
#include <hip/hip_runtime.h>
#include <hip/hip_bf16.h>

#define HEADS  16
#define DIMH   64
#define NBATCH 2
#define SEQ    2048
#define DMODEL 1024
#define MROWS  (NBATCH * SEQ)   // 4096

typedef __attribute__((ext_vector_type(8)))  short bf16x8;
typedef __attribute__((ext_vector_type(4)))  float f32x4;
typedef __attribute__((ext_vector_type(16))) float f32x16;
typedef __attribute__((ext_vector_type(4)))  float float4v;
typedef __attribute__((ext_vector_type(4)))  short short4v;
typedef __attribute__((ext_vector_type(8)))  short short8v;

__device__ inline void glds16(const void* g, void* l) {
    __builtin_amdgcn_global_load_lds(
        (const __attribute__((address_space(1))) unsigned int*)g,
        (__attribute__((address_space(3))) unsigned int*)l, 16, 0, 0);
}

#define WAIT_VMCNT(N) asm volatile("s_waitcnt vmcnt(" #N ")" ::: "memory")
#define BARRIER() do { __builtin_amdgcn_s_barrier(); asm volatile("" ::: "memory"); } while (0)

// ------ prep: hs f32->bf16 cast + 3 weight transposes, ONE launch ---------
__global__ void prep_kernel(const float* __restrict__ hs,
                            const float* __restrict__ Wq,
                            const float* __restrict__ Wkv,
                            const float* __restrict__ Wout,
                            __hip_bfloat16* __restrict__ hsb,
                            __hip_bfloat16* __restrict__ WqT,
                            __hip_bfloat16* __restrict__ WkvT,
                            __hip_bfloat16* __restrict__ WoT) {
    __shared__ float tile[64][65];
    const int tid = threadIdx.x;
    const int bid = blockIdx.x;
    if (bid < 768) {
        const int w = bid >> 8;            // 0..2
        const int tnum = bid & 255;        // 0..255
        const int bx = tnum & 15;          // o-tile
        const int by = tnum >> 4;          // i-tile
        const float* __restrict__ W = (w == 0) ? Wq : (w == 1) ? Wkv : Wout;
        __hip_bfloat16* __restrict__ WT = (w == 0) ? WqT : (w == 1) ? WkvT : WoT;
        const int ty = tid >> 6, tx = tid & 63;
#pragma unroll
        for (int r = 0; r < 16; ++r)
            tile[ty * 16 + r][tx] = W[(size_t)(by * 64 + ty * 16 + r) * DMODEL + bx * 64 + tx];
        __syncthreads();
#pragma unroll
        for (int r = 0; r < 16; ++r)
            WT[(size_t)(bx * 64 + ty * 16 + r) * DMODEL + by * 64 + tx] =
                __float2bfloat16(tile[tx][ty * 16 + r]);
    } else {
        const int cb = bid - 768;          // 0..1023
#pragma unroll
        for (int jj = 0; jj < 4; ++jj) {
            int i = cb * 1024 + jj * 256 + tid;   // float4-group index
            float4v v = reinterpret_cast<const float4v*>(hs)[i];
            union { short4v s; __hip_bfloat16 h[4]; } u;
#pragma unroll
            for (int j = 0; j < 4; ++j) u.h[j] = __float2bfloat16(v[j]);
            reinterpret_cast<short4v*>(hsb)[i] = u.s;
        }
    }
}

// ---- combine: ao = bf16(p0 + p1), bf16 partials, 8 elems/thread ----
__global__ void combine_kernel(const __hip_bfloat16* __restrict__ p0,
                               const __hip_bfloat16* __restrict__ p1,
                               __hip_bfloat16* __restrict__ out, int n8) {
    int i = blockIdx.x * blockDim.x + threadIdx.x;
    if (i >= n8) return;
    union { short8v s; __hip_bfloat16 h[8]; } a, b, u;
    a.s = reinterpret_cast<const short8v*>(p0)[i];
    b.s = reinterpret_cast<const short8v*>(p1)[i];
#pragma unroll
    for (int j = 0; j < 8; ++j)
        u.h[j] = __float2bfloat16(__bfloat162float(a.h[j]) + __bfloat162float(b.h[j]));
    reinterpret_cast<short8v*>(out)[i] = u.s;
}

// -------- fused Q/KV projection GEMM (BM=128, BN=128, grid 512) ------------
// 2 blocks/CU. vtb stored with s-index bits 2&3 swapped within each 16-block
// so the attention kernel's PV fragment chunks are contiguous global bytes.
__launch_bounds__(512, 4)
__global__ void proj_kernel(const __hip_bfloat16* __restrict__ hsb,
                            const __hip_bfloat16* __restrict__ WqT,
                            const __hip_bfloat16* __restrict__ WkvT,
                            __hip_bfloat16* __restrict__ qb,
                            __hip_bfloat16* __restrict__ kb,
                            __hip_bfloat16* __restrict__ vtb) {
    __shared__ __align__(16) char SLDS[49152];
    char (*Alds)[8192] = (char (*)[8192])SLDS;               // 3 x 8KB
    char (*Blds)[8192] = (char (*)[8192])(SLDS + 24576);     // 3 x 8KB
    char* CT = SLDS;                                         // 32KB reuse

    const int tid  = threadIdx.x;         // 0..511
    const int wave = tid >> 6;            // 0..7
    const int lane = tid & 63;
    const int lr = lane & 15;
    const int lk = lane >> 4;
    const int wm = wave >> 1, wn = wave & 1;   // 4M x 2N, wave tile 32x64

    // bijective XCD swizzle: 512 blocks, 64 contiguous ids per XCD
    int bid = blockIdx.x;
    bid = (bid & 7) * 64 + (bid >> 3);
    const int xt = bid & 15;              // q: 0..7, kv: 8..15
    const int mt = bid >> 4;              // 0..31
    const bool is_q = xt < 8;
    const int mbase = mt * 128;
    const int nbase = (xt & 7) * 128;
    const __hip_bfloat16* __restrict__ WT = is_q ? WqT : WkvT;

    const char* __restrict__ Ab = (const char*)(hsb + (size_t)mbase * DMODEL);
    const char* __restrict__ Bb = (const char*)(WT + (size_t)nbase * DMODEL);

    auto stage = [&](int buf, int k0) {
        const size_t colb = (size_t)k0 * 2 + lk * 16;
        const size_t rowoff = (size_t)(wave * 16 + lr) * (DMODEL * 2);
        glds16(Ab + rowoff + colb, &Alds[buf][wave * 1024]);
        glds16(Bb + rowoff + colb, &Blds[buf][wave * 1024]);
    };

    stage(0, 0);
    stage(1, 32);

    f32x4 acc[2][4] = {};
    int c0 = 0;
    for (int t = 0; t < DMODEL / 32; ++t) {
        if (t < DMODEL / 32 - 1) WAIT_VMCNT(2); else WAIT_VMCNT(0);
        BARRIER();
        if (t + 2 < DMODEL / 32) {
            int sb = c0 + 2; if (sb >= 3) sb -= 3;
            stage(sb, (t + 2) * 32);
        }
        bf16x8 af[2], bfr[4];
#pragma unroll
        for (int i = 0; i < 2; ++i)
            af[i] = *reinterpret_cast<const bf16x8*>(&Alds[c0][(wm * 2 + i) * 1024 + lane * 16]);
#pragma unroll
        for (int j = 0; j < 4; ++j)
            bfr[j] = *reinterpret_cast<const bf16x8*>(&Blds[c0][(wn * 4 + j) * 1024 + lane * 16]);
#pragma unroll
        for (int i = 0; i < 2; ++i)
#pragma unroll
            for (int j = 0; j < 4; ++j)
                acc[i][j] = __builtin_amdgcn_mfma_f32_16x16x32_bf16(af[i], bfr[j], acc[i][j], 0, 0, 0);
        c0 = (c0 + 1 == 3) ? 0 : c0 + 1;
    }

    // ================= epilogue via LDS (coalesced stores) =================
    const float qscale = is_q ? 0.125f : 1.0f;   // fold attention scale into Q
    const int b_ = mbase >> 11;
    const int s0 = mbase & (SEQ - 1);
    const int h0 = nbase >> 6;
    BARRIER();   // staging LDS dead

    // 1) acc -> CT [128m][128n] bf16, key = ((m>>2)&7)<<4
#pragma unroll
    for (int i = 0; i < 2; ++i)
#pragma unroll
        for (int j = 0; j < 4; ++j)
#pragma unroll
            for (int r = 0; r < 4; ++r) {
                int m = wm * 32 + i * 16 + lk * 4 + r;
                int n = wn * 64 + j * 16 + lr;
                *reinterpret_cast<__hip_bfloat16*>(
                    &CT[m * 256 + ((n * 2) ^ (((m >> 2) & 7) << 4))]) =
                    __float2bfloat16(acc[i][j][r] * qscale);
            }
    BARRIER();

    // 2) coalesced q/k stores: 8-lane groups write 128B head-segment runs
    __hip_bfloat16* __restrict__ dst0 = is_q ? qb : kb;
#pragma unroll
    for (int p = 0; p < 4; ++p) {
        int g = p * 64 + (tid >> 3);      // 0..255
        int m = g >> 1, hseg = g & 1, o = tid & 7;
        int key = ((m >> 2) & 7) << 4;
        bf16x8 val = *reinterpret_cast<const bf16x8*>(
            &CT[m * 256 + ((hseg * 128 + o * 16) ^ key)]);
        *reinterpret_cast<bf16x8*>(
            &dst0[(((size_t)b_ * HEADS + h0 + hseg) * SEQ + s0 + m) * DIMH + o * 8]) = val;
    }

    if (!is_q) {
        BARRIER();
        // 3) acc -> CT2 [128n][128m] bf16, key2 = ((n&7)<<4)
#pragma unroll
        for (int i = 0; i < 2; ++i)
#pragma unroll
            for (int j = 0; j < 4; ++j)
#pragma unroll
                for (int r = 0; r < 4; ++r) {
                    int m = wm * 32 + i * 16 + lk * 4 + r;
                    int n = wn * 64 + j * 16 + lr;
                    *reinterpret_cast<__hip_bfloat16*>(
                        &CT[n * 256 + ((m * 2) ^ ((n & 7) << 4))]) =
                        __float2bfloat16(acc[i][j][r]);
                }
        BARRIER();
        // 4) coalesced vtb stores, s bits2&3 swapped: dest run t'=16m'+8H+j
#pragma unroll
        for (int p = 0; p < 4; ++p) {
            int g = p * 64 + (tid >> 3);      // 0..255
            int n = g >> 1, half = g & 1, o = tid & 7;
            int key2 = (n & 7) << 4;
            int D = half * 64 + o * 8;
            int mm = D >> 4, H = o & 1;
            union { unsigned long long d[2]; bf16x8 v; } val;
            val.d[0] = *reinterpret_cast<const unsigned long long*>(
                &CT[n * 256 + ((mm * 32 + H * 8) ^ key2)]);
            val.d[1] = *reinterpret_cast<const unsigned long long*>(
                &CT[n * 256 + ((mm * 32 + 16 + H * 8) ^ key2)]);
            int h = h0 + (n >> 6);
            int dh = n & 63;
            *reinterpret_cast<bf16x8*>(
                &vtb[(((size_t)b_ * HEADS + h) * DIMH + dh) * SEQ + s0 + D]) = val.v;
        }
    }
}

// ---- output projection GEMM + bias (BM=64, BN=128, grid 512, f32 out) -----
// 2 blocks/CU. 8 waves as 2M x 4N (wave tile 32x32). A staged by waves 0-3,
// B by all 8; per-wave counted vmcnt (2 or 1).
__launch_bounds__(512, 4)
__global__ void outproj_kernel(const __hip_bfloat16* __restrict__ ao,
                               const __hip_bfloat16* __restrict__ WoT,
                               const float* __restrict__ bout,
                               float* __restrict__ out) {
    __shared__ __align__(16) char Alds[3][4096];
    __shared__ __align__(16) char Blds[3][8192];
    const int tid  = threadIdx.x;
    const int wave = tid >> 6;
    const int lane = tid & 63;
    const int lr = lane & 15;
    const int lk = lane >> 4;
    const int wm = wave >> 2, wn = wave & 3;   // 2M x 4N, wave tile 32x32

    // bijective XCD swizzle: 512 blocks, 64 contiguous ids per XCD
    int bid = blockIdx.x;
    bid = (bid & 7) * 64 + (bid >> 3);
    const int xt = bid & 7;               // n-tile 0..7
    const int mt = bid >> 3;              // m-tile 0..63
    const int mbase = mt * 64;
    const int nbase = xt * 128;

    const char* __restrict__ Ab = (const char*)(ao + (size_t)mbase * DMODEL);
    const char* __restrict__ Bb = (const char*)(WoT + (size_t)nbase * DMODEL);

    auto stage = [&](int buf, int k0) {
        const size_t colb = (size_t)k0 * 2 + lk * 16;
        if (wave < 4)
            glds16(Ab + (size_t)(wave * 16 + lr) * (DMODEL * 2) + colb,
                   &Alds[buf][wave * 1024]);
        glds16(Bb + (size_t)(wave * 16 + lr) * (DMODEL * 2) + colb,
               &Blds[buf][wave * 1024]);
    };

    stage(0, 0);
    stage(1, 32);

    f32x4 acc[2][2] = {};
    int c0 = 0;
    for (int t = 0; t < DMODEL / 32; ++t) {
        if (t < DMODEL / 32 - 1) {
            if (wave < 4) WAIT_VMCNT(2); else WAIT_VMCNT(1);
        } else WAIT_VMCNT(0);
        BARRIER();
        if (t + 2 < DMODEL / 32) {
            int sb = c0 + 2; if (sb >= 3) sb -= 3;
            stage(sb, (t + 2) * 32);
        }
        bf16x8 af[2], bfr[2];
#pragma unroll
        for (int i = 0; i < 2; ++i)
            af[i] = *reinterpret_cast<const bf16x8*>(&Alds[c0][(wm * 2 + i) * 1024 + lane * 16]);
#pragma unroll
        for (int j = 0; j < 2; ++j)
            bfr[j] = *reinterpret_cast<const bf16x8*>(&Blds[c0][(wn * 2 + j) * 1024 + lane * 16]);
#pragma unroll
        for (int i = 0; i < 2; ++i)
#pragma unroll
            for (int j = 0; j < 2; ++j)
                acc[i][j] = __builtin_amdgcn_mfma_f32_16x16x32_bf16(af[i], bfr[j], acc[i][j], 0, 0, 0);
        c0 = (c0 + 1 == 3) ? 0 : c0 + 1;
    }

#pragma unroll
    for (int j = 0; j < 2; ++j) {
        const int n = nbase + wn * 32 + j * 16 + lr;
        const float bias = bout[n];
#pragma unroll
        for (int i = 0; i < 2; ++i) {
#pragma unroll
            for (int r = 0; r < 4; ++r) {
                int m = mbase + wm * 32 + i * 16 + lk * 4 + r;
                out[(size_t)m * DMODEL + n] = acc[i][j][r] + bias;
            }
        }
    }
}

// ------- fused ReLU attention: KVBLK=128 (1 barrier per 128 t) -------------
// grid 256 = 32 bh x 4 qblk x 2 ts; 512 thr; wave owns 64 q x 1024 t.
// 128-t K/V tiles in 16 fragment-order runs each (32KB/buf), 3 buffers (96KB);
// two 64-t compute sub-steps per barrier; counted vmcnt(4).
__launch_bounds__(512, 2)
__global__ void attn_kernel(const __hip_bfloat16* __restrict__ qb,
                            const __hip_bfloat16* __restrict__ kb,
                            const __hip_bfloat16* __restrict__ vtb,
                            __hip_bfloat16* __restrict__ po) {
    __shared__ __align__(16) char Klds[3][16384];
    __shared__ __align__(16) char Vlds[3][16384];
    const int lane = threadIdx.x & 63;
    const int wave = threadIdx.x >> 6;    // 0..7
    const int l32  = lane & 31;
    const int hi   = lane >> 5;

    int bid = blockIdx.x;
    bid = (bid & 7) * 32 + (bid >> 3);    // bijective XCD swizzle (256%8==0)
    const int ts   = bid & 1;             // t-split half
    const int qblk = (bid >> 1) & 3;      // 0..3
    const int bh   = bid >> 3;            // 0..31
    const int b_ = bh >> 4, h = bh & 15;
    const int qbase = qblk * 512 + wave * 64;
    const int tbeg = ts * (SEQ / 2);

    const __hip_bfloat16* __restrict__ Q = qb + (size_t)bh * SEQ * DIMH;
    const char* __restrict__ Kg = (const char*)(kb  + (size_t)bh * SEQ * DIMH);
    const char* __restrict__ Vg = (const char*)(vtb + (size_t)bh * DIMH * SEQ);

    // two q-groups of 32 rows each
    bf16x8 qf[2][4];
#pragma unroll
    for (int g = 0; g < 2; ++g)
#pragma unroll
        for (int ks = 0; ks < 4; ++ks)
            qf[g][ks] = *reinterpret_cast<const bf16x8*>(
                &Q[(size_t)(qbase + g * 32 + l32) * DIMH + ks * 16 + hi * 8]);

    // 128-t tile: 16 K runs + 16 V runs; wave stages K {wave, 8+wave},
    // V {wave, 8+wave} (4 glds).
    auto stage = [&](int buf, int t0) {
        const int krow = (wave >> 2) * 32 + l32;
        const int kcol = (wave & 3) * 32 + hi * 16;
        glds16(Kg + (size_t)(t0 + krow) * 128 + kcol,       &Klds[buf][wave * 1024]);
        glds16(Kg + (size_t)(t0 + 64 + krow) * 128 + kcol,  &Klds[buf][(8 + wave) * 1024]);
        const size_t vrow = (size_t)((wave & 1) * 32 + l32) * (SEQ * 2);
        const int vcol = (wave >> 1) * 32 + hi * 16;
        glds16(Vg + vrow + (size_t)t0 * 2 + vcol,           &Vlds[buf][wave * 1024]);
        glds16(Vg + vrow + (size_t)(t0 + 64) * 2 + vcol,    &Vlds[buf][(8 + wave) * 1024]);
    };

    f32x16 acco[2][2] = {};   // [qgroup][nt]

    // one 64-t sub-step: u=0 -> runs 0..7, u=1 -> runs 8..15
    auto compute = [&](const char* Kc, const char* Vc, int u) {
        const int ro = u * 8192;
        f32x16 sp[2][2] = {};  // [qgroup][t-32-half]
        __builtin_amdgcn_s_setprio(1);
#pragma unroll
        for (int ks = 0; ks < 4; ++ks) {
            bf16x8 k0f = *reinterpret_cast<const bf16x8*>(Kc + ro + ks * 1024 + lane * 16);
            bf16x8 k1f = *reinterpret_cast<const bf16x8*>(Kc + ro + (4 + ks) * 1024 + lane * 16);
            sp[0][0] = __builtin_amdgcn_mfma_f32_32x32x16_bf16(k0f, qf[0][ks], sp[0][0], 0, 0, 0);
            sp[0][1] = __builtin_amdgcn_mfma_f32_32x32x16_bf16(k1f, qf[0][ks], sp[0][1], 0, 0, 0);
            sp[1][0] = __builtin_amdgcn_mfma_f32_32x32x16_bf16(k0f, qf[1][ks], sp[1][0], 0, 0, 0);
            sp[1][1] = __builtin_amdgcn_mfma_f32_32x32x16_bf16(k1f, qf[1][ks], sp[1][1], 0, 0, 0);
        }
#pragma unroll
        for (int kt = 0; kt < 4; ++kt) {
            bf16x8 v0 = *reinterpret_cast<const bf16x8*>(Vc + ro + (kt * 2 + 0) * 1024 + lane * 16);
            bf16x8 v1 = *reinterpret_cast<const bf16x8*>(Vc + ro + (kt * 2 + 1) * 1024 + lane * 16);
            const int rb = (kt & 1) * 8;
#pragma unroll
            for (int g = 0; g < 2; ++g) {
                union { __hip_bfloat16 hh[8]; bf16x8 v; } pa;
#pragma unroll
                for (int j = 0; j < 8; ++j) {
                    float x = (kt < 2) ? sp[g][0][rb + j] : sp[g][1][rb + j];
                    pa.hh[j] = __float2bfloat16(fmaxf(x, 0.f));
                }
                acco[g][0] = __builtin_amdgcn_mfma_f32_32x32x16_bf16(pa.v, v0, acco[g][0], 0, 0, 0);
                acco[g][1] = __builtin_amdgcn_mfma_f32_32x32x16_bf16(pa.v, v1, acco[g][1], 0, 0, 0);
            }
        }
        __builtin_amdgcn_s_setprio(0);
    };

    const int NT = SEQ / 2 / 128;   // 8 tiles per t-half
    stage(0, tbeg);
    stage(1, tbeg + 128);

    for (int t = 0; t < NT; ++t) {
        if (t < NT - 1) WAIT_VMCNT(4); else WAIT_VMCNT(0);
        BARRIER();
        if (t + 2 < NT) {
            int sb = t + 2; sb -= (sb / 3) * 3;   // (t+2)%3
            stage(sb, tbeg + (t + 2) * 128);
        }
        const int c0 = t % 3;
        compute(Klds[c0], Vlds[c0], 0);
        compute(Klds[c0], Vlds[c0], 1);
    }

    // ---- epilogue: bf16 partial, row q = qbase + g*32 + (r&3)+8*(r>>2)+4*hi ----
    __hip_bfloat16* __restrict__ PO = po + (size_t)ts * MROWS * DMODEL;
#pragma unroll
    for (int g = 0; g < 2; ++g)
#pragma unroll
        for (int nt = 0; nt < 2; ++nt)
#pragma unroll
            for (int r = 0; r < 16; ++r) {
                int q = qbase + g * 32 + (r & 3) + 8 * (r >> 2) + 4 * hi;
                PO[(size_t)(b_ * SEQ + q) * DMODEL + h * 64 + nt * 32 + l32] =
                    __float2bfloat16(acco[g][nt][r]);
            }
}

extern "C" void kernel_launch(void* const* d_in, const int* in_sizes, int n_in,
                              void* d_out, int out_size, void* d_ws, size_t ws_size,
                              hipStream_t stream) {
    const float* hs   = (const float*)d_in[0];
    const float* Wq   = (const float*)d_in[1];
    const float* Wkv  = (const float*)d_in[2];
    const float* Wout = (const float*)d_in[3];
    const float* bout = (const float*)d_in[4];
    float* out = (float*)d_out;

    char* ws = (char*)d_ws;
    size_t off = 0;
    auto alloc = [&](size_t bytes) { char* p = ws + off; off += bytes; return p; };
    __hip_bfloat16* hsb  = (__hip_bfloat16*)alloc((size_t)MROWS * DMODEL * 2); // dead after proj
    __hip_bfloat16* WqT  = (__hip_bfloat16*)alloc((size_t)DMODEL * DMODEL * 2);
    __hip_bfloat16* WkvT = (__hip_bfloat16*)alloc((size_t)DMODEL * DMODEL * 2);
    __hip_bfloat16* WoT  = (__hip_bfloat16*)alloc((size_t)DMODEL * DMODEL * 2);
    __hip_bfloat16* qb   = (__hip_bfloat16*)alloc((size_t)MROWS * DMODEL * 2);
    __hip_bfloat16* kb   = (__hip_bfloat16*)alloc((size_t)MROWS * DMODEL * 2);
    __hip_bfloat16* vtb  = (__hip_bfloat16*)alloc((size_t)MROWS * DMODEL * 2);
    __hip_bfloat16* po   = (__hip_bfloat16*)alloc((size_t)2 * MROWS * DMODEL * 2); // 16MB bf16
    __hip_bfloat16* ao   = hsb;  // alias: hs_bf16 is dead once attention runs

    // 1. fused cast + transposes: ONE launch
    prep_kernel<<<1792, 256, 0, stream>>>(hs, Wq, Wkv, Wout, hsb, WqT, WkvT, WoT);

    // 2. fused Q/KV projection (Q pre-scaled by 1/8): 512 blocks x 512 thr
    proj_kernel<<<512, 512, 0, stream>>>(hsb, WqT, WkvT, qb, kb, vtb);

    // 3. fused relu attention: 256 blocks x 512 thr, KVBLK=128, t-split
    attn_kernel<<<256, 512, 0, stream>>>(qb, kb, vtb, po);

    // 4. combine bf16 partials -> bf16 ao
    combine_kernel<<<(MROWS * DMODEL / 8 + 255) / 256, 256, 0, stream>>>(
        po, po + (size_t)MROWS * DMODEL, ao, MROWS * DMODEL / 8);

    // 5. output projection: 512 blocks x 512 thr (BM=64, 2 blocks/CU)
    outproj_kernel<<<512, 512, 0, stream>>>(ao, WoT, bout, out);
}

// Round 22
// 110.506 us; speedup vs baseline: 1.0837x; 1.0175x over previous
//
#include <hip/hip_runtime.h>
#include <hip/hip_bf16.h>

#define HEADS  16
#define DIMH   64
#define NBATCH 2
#define SEQ    2048
#define DMODEL 1024
#define MROWS  (NBATCH * SEQ)   // 4096

typedef __attribute__((ext_vector_type(8)))  short bf16x8;
typedef __attribute__((ext_vector_type(4)))  float f32x4;
typedef __attribute__((ext_vector_type(16))) float f32x16;
typedef __attribute__((ext_vector_type(4)))  float float4v;
typedef __attribute__((ext_vector_type(4)))  short short4v;
typedef __attribute__((ext_vector_type(8)))  short short8v;

__device__ inline void glds16(const void* g, void* l) {
    __builtin_amdgcn_global_load_lds(
        (const __attribute__((address_space(1))) unsigned int*)g,
        (__attribute__((address_space(3))) unsigned int*)l, 16, 0, 0);
}

#define WAIT_VMCNT(N) asm volatile("s_waitcnt vmcnt(" #N ")" ::: "memory")
#define BARRIER() do { __builtin_amdgcn_s_barrier(); asm volatile("" ::: "memory"); } while (0)

// ------ prep: hs f32->bf16 cast + 3 weight transposes, ONE launch ---------
__global__ void prep_kernel(const float* __restrict__ hs,
                            const float* __restrict__ Wq,
                            const float* __restrict__ Wkv,
                            const float* __restrict__ Wout,
                            __hip_bfloat16* __restrict__ hsb,
                            __hip_bfloat16* __restrict__ WqT,
                            __hip_bfloat16* __restrict__ WkvT,
                            __hip_bfloat16* __restrict__ WoT) {
    __shared__ float tile[64][65];
    const int tid = threadIdx.x;
    const int bid = blockIdx.x;
    if (bid < 768) {
        const int w = bid >> 8;            // 0..2
        const int tnum = bid & 255;        // 0..255
        const int bx = tnum & 15;          // o-tile
        const int by = tnum >> 4;          // i-tile
        const float* __restrict__ W = (w == 0) ? Wq : (w == 1) ? Wkv : Wout;
        __hip_bfloat16* __restrict__ WT = (w == 0) ? WqT : (w == 1) ? WkvT : WoT;
        const int ty = tid >> 6, tx = tid & 63;
#pragma unroll
        for (int r = 0; r < 16; ++r)
            tile[ty * 16 + r][tx] = W[(size_t)(by * 64 + ty * 16 + r) * DMODEL + bx * 64 + tx];
        __syncthreads();
#pragma unroll
        for (int r = 0; r < 16; ++r)
            WT[(size_t)(bx * 64 + ty * 16 + r) * DMODEL + by * 64 + tx] =
                __float2bfloat16(tile[tx][ty * 16 + r]);
    } else {
        const int cb = bid - 768;          // 0..1023
#pragma unroll
        for (int jj = 0; jj < 4; ++jj) {
            int i = cb * 1024 + jj * 256 + tid;   // float4-group index
            float4v v = reinterpret_cast<const float4v*>(hs)[i];
            union { short4v s; __hip_bfloat16 h[4]; } u;
#pragma unroll
            for (int j = 0; j < 4; ++j) u.h[j] = __float2bfloat16(v[j]);
            reinterpret_cast<short4v*>(hsb)[i] = u.s;
        }
    }
}

// ---- combine: ao = bf16(p0 + p1), bf16 partials, 8 elems/thread ----
__global__ void combine_kernel(const __hip_bfloat16* __restrict__ p0,
                               const __hip_bfloat16* __restrict__ p1,
                               __hip_bfloat16* __restrict__ out, int n8) {
    int i = blockIdx.x * blockDim.x + threadIdx.x;
    if (i >= n8) return;
    union { short8v s; __hip_bfloat16 h[8]; } a, b, u;
    a.s = reinterpret_cast<const short8v*>(p0)[i];
    b.s = reinterpret_cast<const short8v*>(p1)[i];
#pragma unroll
    for (int j = 0; j < 8; ++j)
        u.h[j] = __float2bfloat16(__bfloat162float(a.h[j]) + __bfloat162float(b.h[j]));
    reinterpret_cast<short8v*>(out)[i] = u.s;
}

// ---- fused Q/KV projection GEMM (BM=128, BN=128, BK=64, grid 512) ---------
// 2-buffer/2-barrier counted schedule: 16 intervals x 16 MFMA (vs 32 x 8).
// 64KB LDS -> 2 blocks/CU at lb(512,4). vtb stored with s bits2&3 swapped.
__launch_bounds__(512, 4)
__global__ void proj_kernel(const __hip_bfloat16* __restrict__ hsb,
                            const __hip_bfloat16* __restrict__ WqT,
                            const __hip_bfloat16* __restrict__ WkvT,
                            __hip_bfloat16* __restrict__ qb,
                            __hip_bfloat16* __restrict__ kb,
                            __hip_bfloat16* __restrict__ vtb) {
    __shared__ __align__(16) char SLDS[65536];
    char (*Alds)[16384] = (char (*)[16384])SLDS;             // 2 x 16KB
    char (*Blds)[16384] = (char (*)[16384])(SLDS + 32768);   // 2 x 16KB
    char* CT = SLDS;                                         // 32KB reuse

    const int tid  = threadIdx.x;         // 0..511
    const int wave = tid >> 6;            // 0..7
    const int lane = tid & 63;
    const int lr = lane & 15;
    const int lk = lane >> 4;
    const int wm = wave >> 1, wn = wave & 1;   // 4M x 2N, wave tile 32x64

    // bijective XCD swizzle: 512 blocks, 64 contiguous ids per XCD
    int bid = blockIdx.x;
    bid = (bid & 7) * 64 + (bid >> 3);
    const int xt = bid & 15;              // q: 0..7, kv: 8..15
    const int mt = bid >> 4;              // 0..31
    const bool is_q = xt < 8;
    const int mbase = mt * 128;
    const int nbase = (xt & 7) * 128;
    const __hip_bfloat16* __restrict__ WT = is_q ? WqT : WkvT;

    const char* __restrict__ Ab = (const char*)(hsb + (size_t)mbase * DMODEL);
    const char* __restrict__ Bb = (const char*)(WT + (size_t)nbase * DMODEL);

    // stage one BK=64 tile: kchunk c (32 k) of frag-block w at [c*8192 + w*1024]
    auto stage = [&](int buf, int k0) {
        const size_t rowoff = (size_t)(wave * 16 + lr) * (DMODEL * 2);
        const size_t c0b = (size_t)k0 * 2 + lk * 16;
        const size_t c1b = (size_t)(k0 + 32) * 2 + lk * 16;
        glds16(Ab + rowoff + c0b, &Alds[buf][wave * 1024]);
        glds16(Ab + rowoff + c1b, &Alds[buf][8192 + wave * 1024]);
        glds16(Bb + rowoff + c0b, &Blds[buf][wave * 1024]);
        glds16(Bb + rowoff + c1b, &Blds[buf][8192 + wave * 1024]);
    };

    stage(0, 0);

    f32x4 acc[2][4] = {};
    const int NT = DMODEL / 64;   // 16
    for (int t = 0; t < NT; ++t) {
        if (t + 1 < NT) stage((t + 1) & 1, (t + 1) * 64);
        if (t + 1 < NT) WAIT_VMCNT(4); else WAIT_VMCNT(0);
        BARRIER();
        const int c0 = t & 1;
#pragma unroll
        for (int kc = 0; kc < 2; ++kc) {
            bf16x8 af[2], bfr[4];
#pragma unroll
            for (int i = 0; i < 2; ++i)
                af[i] = *reinterpret_cast<const bf16x8*>(
                    &Alds[c0][kc * 8192 + (wm * 2 + i) * 1024 + lane * 16]);
#pragma unroll
            for (int j = 0; j < 4; ++j)
                bfr[j] = *reinterpret_cast<const bf16x8*>(
                    &Blds[c0][kc * 8192 + (wn * 4 + j) * 1024 + lane * 16]);
#pragma unroll
            for (int i = 0; i < 2; ++i)
#pragma unroll
                for (int j = 0; j < 4; ++j)
                    acc[i][j] = __builtin_amdgcn_mfma_f32_16x16x32_bf16(af[i], bfr[j], acc[i][j], 0, 0, 0);
        }
        BARRIER();   // readers done: next iter may overwrite this buffer
    }

    // ================= epilogue via LDS (coalesced stores) =================
    const float qscale = is_q ? 0.125f : 1.0f;   // fold attention scale into Q
    const int b_ = mbase >> 11;
    const int s0 = mbase & (SEQ - 1);
    const int h0 = nbase >> 6;

    // 1) acc -> CT [128m][128n] bf16, key = ((m>>2)&7)<<4
#pragma unroll
    for (int i = 0; i < 2; ++i)
#pragma unroll
        for (int j = 0; j < 4; ++j)
#pragma unroll
            for (int r = 0; r < 4; ++r) {
                int m = wm * 32 + i * 16 + lk * 4 + r;
                int n = wn * 64 + j * 16 + lr;
                *reinterpret_cast<__hip_bfloat16*>(
                    &CT[m * 256 + ((n * 2) ^ (((m >> 2) & 7) << 4))]) =
                    __float2bfloat16(acc[i][j][r] * qscale);
            }
    BARRIER();

    // 2) coalesced q/k stores: 8-lane groups write 128B head-segment runs
    __hip_bfloat16* __restrict__ dst0 = is_q ? qb : kb;
#pragma unroll
    for (int p = 0; p < 4; ++p) {
        int g = p * 64 + (tid >> 3);      // 0..255
        int m = g >> 1, hseg = g & 1, o = tid & 7;
        int key = ((m >> 2) & 7) << 4;
        bf16x8 val = *reinterpret_cast<const bf16x8*>(
            &CT[m * 256 + ((hseg * 128 + o * 16) ^ key)]);
        *reinterpret_cast<bf16x8*>(
            &dst0[(((size_t)b_ * HEADS + h0 + hseg) * SEQ + s0 + m) * DIMH + o * 8]) = val;
    }

    if (!is_q) {
        BARRIER();
        // 3) acc -> CT2 [128n][128m] bf16, key2 = ((n&7)<<4)
#pragma unroll
        for (int i = 0; i < 2; ++i)
#pragma unroll
            for (int j = 0; j < 4; ++j)
#pragma unroll
                for (int r = 0; r < 4; ++r) {
                    int m = wm * 32 + i * 16 + lk * 4 + r;
                    int n = wn * 64 + j * 16 + lr;
                    *reinterpret_cast<__hip_bfloat16*>(
                        &CT[n * 256 + ((m * 2) ^ ((n & 7) << 4))]) =
                        __float2bfloat16(acc[i][j][r]);
                }
        BARRIER();
        // 4) coalesced vtb stores, s bits2&3 swapped: dest run t'=16m'+8H+j
#pragma unroll
        for (int p = 0; p < 4; ++p) {
            int g = p * 64 + (tid >> 3);      // 0..255
            int n = g >> 1, half = g & 1, o = tid & 7;
            int key2 = (n & 7) << 4;
            int D = half * 64 + o * 8;
            int mm = D >> 4, H = o & 1;
            union { unsigned long long d[2]; bf16x8 v; } val;
            val.d[0] = *reinterpret_cast<const unsigned long long*>(
                &CT[n * 256 + ((mm * 32 + H * 8) ^ key2)]);
            val.d[1] = *reinterpret_cast<const unsigned long long*>(
                &CT[n * 256 + ((mm * 32 + 16 + H * 8) ^ key2)]);
            int h = h0 + (n >> 6);
            int dh = n & 63;
            *reinterpret_cast<bf16x8*>(
                &vtb[(((size_t)b_ * HEADS + h) * DIMH + dh) * SEQ + s0 + D]) = val.v;
        }
    }
}

// ---- output projection GEMM + bias (BM=64, BN=128, BK=64, grid 512) -------
// 2-buffer/2-barrier counted schedule; 48KB LDS -> 2 blocks/CU at lb(512,4).
__launch_bounds__(512, 4)
__global__ void outproj_kernel(const __hip_bfloat16* __restrict__ ao,
                               const __hip_bfloat16* __restrict__ WoT,
                               const float* __restrict__ bout,
                               float* __restrict__ out) {
    __shared__ __align__(16) char Alds[2][8192];    // 64x64 bf16
    __shared__ __align__(16) char Blds[2][16384];   // 128x64 bf16
    const int tid  = threadIdx.x;
    const int wave = tid >> 6;
    const int lane = tid & 63;
    const int lr = lane & 15;
    const int lk = lane >> 4;
    const int wm = wave >> 2, wn = wave & 3;   // 2M x 4N, wave tile 32x32

    // bijective XCD swizzle: 512 blocks, 64 contiguous ids per XCD
    int bid = blockIdx.x;
    bid = (bid & 7) * 64 + (bid >> 3);
    const int xt = bid & 7;               // n-tile 0..7
    const int mt = bid >> 3;              // m-tile 0..63
    const int mbase = mt * 64;
    const int nbase = xt * 128;

    const char* __restrict__ Ab = (const char*)(ao + (size_t)mbase * DMODEL);
    const char* __restrict__ Bb = (const char*)(WoT + (size_t)nbase * DMODEL);

    // A: 8 frag-blocks (4 rows-of-16 x 2 kchunks); wave w stages fb (w&3),
    // kchunk (w>>2): dest (w>>2)*4096 + (w&3)*1024. B: wave stages fb w for
    // both kchunks: dest kc*8192 + w*1024. 3 glds/wave/stage.
    auto stage = [&](int buf, int k0) {
        const size_t acol = (size_t)(k0 + (wave >> 2) * 32) * 2 + lk * 16;
        glds16(Ab + (size_t)((wave & 3) * 16 + lr) * (DMODEL * 2) + acol,
               &Alds[buf][(wave >> 2) * 4096 + (wave & 3) * 1024]);
        const size_t rowoff = (size_t)(wave * 16 + lr) * (DMODEL * 2);
        glds16(Bb + rowoff + (size_t)k0 * 2 + lk * 16,        &Blds[buf][wave * 1024]);
        glds16(Bb + rowoff + (size_t)(k0 + 32) * 2 + lk * 16, &Blds[buf][8192 + wave * 1024]);
    };

    stage(0, 0);

    f32x4 acc[2][2] = {};
    const int NT = DMODEL / 64;   // 16
    for (int t = 0; t < NT; ++t) {
        if (t + 1 < NT) stage((t + 1) & 1, (t + 1) * 64);
        if (t + 1 < NT) WAIT_VMCNT(3); else WAIT_VMCNT(0);
        BARRIER();
        const int c0 = t & 1;
#pragma unroll
        for (int kc = 0; kc < 2; ++kc) {
            bf16x8 af[2], bfr[2];
#pragma unroll
            for (int i = 0; i < 2; ++i)
                af[i] = *reinterpret_cast<const bf16x8*>(
                    &Alds[c0][kc * 4096 + (wm * 2 + i) * 1024 + lane * 16]);
#pragma unroll
            for (int j = 0; j < 2; ++j)
                bfr[j] = *reinterpret_cast<const bf16x8*>(
                    &Blds[c0][kc * 8192 + (wn * 2 + j) * 1024 + lane * 16]);
#pragma unroll
            for (int i = 0; i < 2; ++i)
#pragma unroll
                for (int j = 0; j < 2; ++j)
                    acc[i][j] = __builtin_amdgcn_mfma_f32_16x16x32_bf16(af[i], bfr[j], acc[i][j], 0, 0, 0);
        }
        BARRIER();
    }

#pragma unroll
    for (int j = 0; j < 2; ++j) {
        const int n = nbase + wn * 32 + j * 16 + lr;
        const float bias = bout[n];
#pragma unroll
        for (int i = 0; i < 2; ++i) {
#pragma unroll
            for (int r = 0; r < 4; ++r) {
                int m = mbase + wm * 32 + i * 16 + lk * 4 + r;
                out[(size_t)m * DMODEL + n] = acc[i][j][r] + bias;
            }
        }
    }
}

// ------- fused ReLU attention: KVBLK=128 (1 barrier per 128 t) -------------
// grid 256 = 32 bh x 4 qblk x 2 ts; 512 thr; wave owns 64 q x 1024 t.
// 128-t K/V tiles in 16 fragment-order runs each (32KB/buf), 3 buffers (96KB);
// two 64-t compute sub-steps per barrier; counted vmcnt(4).
__launch_bounds__(512, 2)
__global__ void attn_kernel(const __hip_bfloat16* __restrict__ qb,
                            const __hip_bfloat16* __restrict__ kb,
                            const __hip_bfloat16* __restrict__ vtb,
                            __hip_bfloat16* __restrict__ po) {
    __shared__ __align__(16) char Klds[3][16384];
    __shared__ __align__(16) char Vlds[3][16384];
    const int lane = threadIdx.x & 63;
    const int wave = threadIdx.x >> 6;    // 0..7
    const int l32  = lane & 31;
    const int hi   = lane >> 5;

    int bid = blockIdx.x;
    bid = (bid & 7) * 32 + (bid >> 3);    // bijective XCD swizzle (256%8==0)
    const int ts   = bid & 1;             // t-split half
    const int qblk = (bid >> 1) & 3;      // 0..3
    const int bh   = bid >> 3;            // 0..31
    const int b_ = bh >> 4, h = bh & 15;
    const int qbase = qblk * 512 + wave * 64;
    const int tbeg = ts * (SEQ / 2);

    const __hip_bfloat16* __restrict__ Q = qb + (size_t)bh * SEQ * DIMH;
    const char* __restrict__ Kg = (const char*)(kb  + (size_t)bh * SEQ * DIMH);
    const char* __restrict__ Vg = (const char*)(vtb + (size_t)bh * DIMH * SEQ);

    // two q-groups of 32 rows each
    bf16x8 qf[2][4];
#pragma unroll
    for (int g = 0; g < 2; ++g)
#pragma unroll
        for (int ks = 0; ks < 4; ++ks)
            qf[g][ks] = *reinterpret_cast<const bf16x8*>(
                &Q[(size_t)(qbase + g * 32 + l32) * DIMH + ks * 16 + hi * 8]);

    // 128-t tile: 16 K runs + 16 V runs; wave stages K {wave, 8+wave},
    // V {wave, 8+wave} (4 glds).
    auto stage = [&](int buf, int t0) {
        const int krow = (wave >> 2) * 32 + l32;
        const int kcol = (wave & 3) * 32 + hi * 16;
        glds16(Kg + (size_t)(t0 + krow) * 128 + kcol,       &Klds[buf][wave * 1024]);
        glds16(Kg + (size_t)(t0 + 64 + krow) * 128 + kcol,  &Klds[buf][(8 + wave) * 1024]);
        const size_t vrow = (size_t)((wave & 1) * 32 + l32) * (SEQ * 2);
        const int vcol = (wave >> 1) * 32 + hi * 16;
        glds16(Vg + vrow + (size_t)t0 * 2 + vcol,           &Vlds[buf][wave * 1024]);
        glds16(Vg + vrow + (size_t)(t0 + 64) * 2 + vcol,    &Vlds[buf][(8 + wave) * 1024]);
    };

    f32x16 acco[2][2] = {};   // [qgroup][nt]

    // one 64-t sub-step: u=0 -> runs 0..7, u=1 -> runs 8..15
    auto compute = [&](const char* Kc, const char* Vc, int u) {
        const int ro = u * 8192;
        f32x16 sp[2][2] = {};  // [qgroup][t-32-half]
        __builtin_amdgcn_s_setprio(1);
#pragma unroll
        for (int ks = 0; ks < 4; ++ks) {
            bf16x8 k0f = *reinterpret_cast<const bf16x8*>(Kc + ro + ks * 1024 + lane * 16);
            bf16x8 k1f = *reinterpret_cast<const bf16x8*>(Kc + ro + (4 + ks) * 1024 + lane * 16);
            sp[0][0] = __builtin_amdgcn_mfma_f32_32x32x16_bf16(k0f, qf[0][ks], sp[0][0], 0, 0, 0);
            sp[0][1] = __builtin_amdgcn_mfma_f32_32x32x16_bf16(k1f, qf[0][ks], sp[0][1], 0, 0, 0);
            sp[1][0] = __builtin_amdgcn_mfma_f32_32x32x16_bf16(k0f, qf[1][ks], sp[1][0], 0, 0, 0);
            sp[1][1] = __builtin_amdgcn_mfma_f32_32x32x16_bf16(k1f, qf[1][ks], sp[1][1], 0, 0, 0);
        }
#pragma unroll
        for (int kt = 0; kt < 4; ++kt) {
            bf16x8 v0 = *reinterpret_cast<const bf16x8*>(Vc + ro + (kt * 2 + 0) * 1024 + lane * 16);
            bf16x8 v1 = *reinterpret_cast<const bf16x8*>(Vc + ro + (kt * 2 + 1) * 1024 + lane * 16);
            const int rb = (kt & 1) * 8;
#pragma unroll
            for (int g = 0; g < 2; ++g) {
                union { __hip_bfloat16 hh[8]; bf16x8 v; } pa;
#pragma unroll
                for (int j = 0; j < 8; ++j) {
                    float x = (kt < 2) ? sp[g][0][rb + j] : sp[g][1][rb + j];
                    pa.hh[j] = __float2bfloat16(fmaxf(x, 0.f));
                }
                acco[g][0] = __builtin_amdgcn_mfma_f32_32x32x16_bf16(pa.v, v0, acco[g][0], 0, 0, 0);
                acco[g][1] = __builtin_amdgcn_mfma_f32_32x32x16_bf16(pa.v, v1, acco[g][1], 0, 0, 0);
            }
        }
        __builtin_amdgcn_s_setprio(0);
    };

    const int NT = SEQ / 2 / 128;   // 8 tiles per t-half
    stage(0, tbeg);
    stage(1, tbeg + 128);

    for (int t = 0; t < NT; ++t) {
        if (t < NT - 1) WAIT_VMCNT(4); else WAIT_VMCNT(0);
        BARRIER();
        if (t + 2 < NT) {
            int sb = t + 2; sb -= (sb / 3) * 3;   // (t+2)%3
            stage(sb, tbeg + (t + 2) * 128);
        }
        const int c0 = t % 3;
        compute(Klds[c0], Vlds[c0], 0);
        compute(Klds[c0], Vlds[c0], 1);
    }

    // ---- epilogue: bf16 partial, row q = qbase + g*32 + (r&3)+8*(r>>2)+4*hi ----
    __hip_bfloat16* __restrict__ PO = po + (size_t)ts * MROWS * DMODEL;
#pragma unroll
    for (int g = 0; g < 2; ++g)
#pragma unroll
        for (int nt = 0; nt < 2; ++nt)
#pragma unroll
            for (int r = 0; r < 16; ++r) {
                int q = qbase + g * 32 + (r & 3) + 8 * (r >> 2) + 4 * hi;
                PO[(size_t)(b_ * SEQ + q) * DMODEL + h * 64 + nt * 32 + l32] =
                    __float2bfloat16(acco[g][nt][r]);
            }
}

extern "C" void kernel_launch(void* const* d_in, const int* in_sizes, int n_in,
                              void* d_out, int out_size, void* d_ws, size_t ws_size,
                              hipStream_t stream) {
    const float* hs   = (const float*)d_in[0];
    const float* Wq   = (const float*)d_in[1];
    const float* Wkv  = (const float*)d_in[2];
    const float* Wout = (const float*)d_in[3];
    const float* bout = (const float*)d_in[4];
    float* out = (float*)d_out;

    char* ws = (char*)d_ws;
    size_t off = 0;
    auto alloc = [&](size_t bytes) { char* p = ws + off; off += bytes; return p; };
    __hip_bfloat16* hsb  = (__hip_bfloat16*)alloc((size_t)MROWS * DMODEL * 2); // dead after proj
    __hip_bfloat16* WqT  = (__hip_bfloat16*)alloc((size_t)DMODEL * DMODEL * 2);
    __hip_bfloat16* WkvT = (__hip_bfloat16*)alloc((size_t)DMODEL * DMODEL * 2);
    __hip_bfloat16* WoT  = (__hip_bfloat16*)alloc((size_t)DMODEL * DMODEL * 2);
    __hip_bfloat16* qb   = (__hip_bfloat16*)alloc((size_t)MROWS * DMODEL * 2);
    __hip_bfloat16* kb   = (__hip_bfloat16*)alloc((size_t)MROWS * DMODEL * 2);
    __hip_bfloat16* vtb  = (__hip_bfloat16*)alloc((size_t)MROWS * DMODEL * 2);
    __hip_bfloat16* po   = (__hip_bfloat16*)alloc((size_t)2 * MROWS * DMODEL * 2); // 16MB bf16
    __hip_bfloat16* ao   = hsb;  // alias: hs_bf16 is dead once attention runs

    // 1. fused cast + transposes: ONE launch
    prep_kernel<<<1792, 256, 0, stream>>>(hs, Wq, Wkv, Wout, hsb, WqT, WkvT, WoT);

    // 2. fused Q/KV projection (Q pre-scaled by 1/8): 512 blocks x 512 thr
    proj_kernel<<<512, 512, 0, stream>>>(hsb, WqT, WkvT, qb, kb, vtb);

    // 3. fused relu attention: 256 blocks x 512 thr, KVBLK=128, t-split
    attn_kernel<<<256, 512, 0, stream>>>(qb, kb, vtb, po);

    // 4. combine bf16 partials -> bf16 ao
    combine_kernel<<<(MROWS * DMODEL / 8 + 255) / 256, 256, 0, stream>>>(
        po, po + (size_t)MROWS * DMODEL, ao, MROWS * DMODEL / 8);

    // 5. output projection: 512 blocks x 512 thr (BM=64, BK=64, 2 blocks/CU)
    outproj_kernel<<<512, 512, 0, stream>>>(ao, WoT, bout, out);
}